// Round 20
// baseline (340.726 us; speedup 1.0000x reference)
//
#include <hip/hip_runtime.h>

#define BATCH   1048576
#define IN_DIM  64
#define OUT_DIM 16
#define NBLK    4096      // 4096 blocks x 4 waves = 16384 waves
#define NWTOT   16384
#define TPERW   4         // 65536 16-row tiles / 16384 waves

typedef __attribute__((ext_vector_type(8))) short short8;  // 8 bf16 = 4 VGPR
typedef __attribute__((ext_vector_type(4))) float f32x4;   // MFMA accumulator

// ---------------------------------------------------------------------------
// Kernel 1: Ct[k*16+i] = C[i][k] where C = (A A^T)^-1 A  (validated R1-R18).
// ---------------------------------------------------------------------------
__global__ __launch_bounds__(256) void precompute_kernel(
    const float* __restrict__ A, float* __restrict__ ws)
{
    __shared__ float sA[16][64];
    __shared__ float M[16][32];   // [S | I]
    __shared__ float fac[16];
    __shared__ int piv;

    const int tid = threadIdx.x;

    for (int i = tid; i < 1024; i += 256) sA[i >> 6][i & 63] = A[i];
    __syncthreads();

    {
        const int i = tid >> 4, j = tid & 15;
        float s = 0.f;
        #pragma unroll
        for (int k = 0; k < 64; ++k) s = fmaf(sA[i][k], sA[j][k], s);
        M[i][j] = s;
        M[i][16 + j] = (i == j) ? 1.f : 0.f;
    }
    __syncthreads();

    for (int p = 0; p < 16; ++p) {
        if (tid == 0) {
            int best = p;
            float bv = fabsf(M[p][p]);
            for (int r = p + 1; r < 16; ++r) {
                float v = fabsf(M[r][p]);
                if (v > bv) { bv = v; best = r; }
            }
            piv = best;
        }
        __syncthreads();
        if (tid < 32) {
            const int pr = piv;
            if (pr != p) { float t = M[p][tid]; M[p][tid] = M[pr][tid]; M[pr][tid] = t; }
        }
        __syncthreads();
        const float pv = M[p][p];
        __syncthreads();
        if (tid < 32) M[p][tid] *= (1.0f / pv);
        __syncthreads();
        if (tid < 16) fac[tid] = M[tid][p];
        __syncthreads();
        for (int e = tid; e < 512; e += 256) {
            const int r = e >> 5, c = e & 31;
            if (r != p) M[r][c] = fmaf(-fac[r], M[p][c], M[r][c]);
        }
        __syncthreads();
    }

    for (int e = tid; e < 1024; e += 256) {
        const int k = e >> 4, i = e & 15;
        float s = 0.f;
        #pragma unroll
        for (int j = 0; j < 16; ++j) s = fmaf(M[i][16 + j], sA[j][k], s);
        ws[e] = s;
    }
}

// ---------------------------------------------------------------------------
// bf16 truncation-split packing (validated R13-R18). hi*hi exact in f32 MFMA.
// ---------------------------------------------------------------------------
__device__ __forceinline__ unsigned pack2(float a, float b, bool lo) {
    unsigned ua = __float_as_uint(a), ub = __float_as_uint(b);
    if (lo) {
        ua = __float_as_uint(a - __uint_as_float(ua & 0xFFFF0000u));
        ub = __float_as_uint(b - __uint_as_float(ub & 0xFFFF0000u));
    }
    return (ua >> 16) | (ub & 0xFFFF0000u);
}
__device__ __forceinline__ short8 pack8(float4 p, float4 q, bool lo) {
    union { short8 s; unsigned u[4]; } r;
    r.u[0] = pack2(p.x, p.y, lo);
    r.u[1] = pack2(p.z, p.w, lo);
    r.u[2] = pack2(q.x, q.y, lo);
    r.u[3] = pack2(q.z, q.w, lo);
    return r.s;
}

__device__ __forceinline__ void nt_store4(const float4 v, float4* p) {
    f32x4 w = {v.x, v.y, v.z, v.w};
    __builtin_nontemporal_store(w, reinterpret_cast<f32x4*>(p));
}

#define MF(a, bb, cc) __builtin_amdgcn_mfma_f32_16x16x32_bf16((a), (bb), (cc), 0, 0, 0)

// ---------------------------------------------------------------------------
// Kernel 2: R18 transposed-MFMA math, occupancy-max layout (R19 retry).
//  - yT pad-free with XOR swizzle col^row; tb pad 5->4. LDS = 20 KB/block
//    EXACTLY -> 8 resident blocks/CU = 32 waves/CU (R18: 22.5 KB -> 7,
//    measured occupancy 41% -> latency-hiding capacity was the wall).
//  - __launch_bounds__(256,8) pins VGPR<=64 (R18 already sits at 64).
//  - staged 1KB stores NONTEMPORAL (out is write-once; keep 268 MB of dead
//    lines out of L2/L3 so y stays cached).
// ---------------------------------------------------------------------------
__global__ __launch_bounds__(256, 8) void apply_kernel(
    const float* __restrict__ y, const float* __restrict__ b,
    const float* __restrict__ A, const float* __restrict__ ws,
    float* __restrict__ out)
{
    __shared__ float4 yT[4][16][16];   // y tile, XOR-swizzled: [row][col^row]
    __shared__ float4 tb[4][16][4];    // t^T tile (row lh, 4 float4)

    const int tid = threadIdx.x;
    const int wv = tid >> 6, l = tid & 63;
    const int lh = l & 15, lg = l >> 4;
    const int hf = lg & 1;
    const bool lolane = (lg >= 2);

    const float4* __restrict__ y4  = reinterpret_cast<const float4*>(y);
    const float4* __restrict__ b4  = reinterpret_cast<const float4*>(b);
    const float4* __restrict__ A4  = reinterpret_cast<const float4*>(A);
    const float4* __restrict__ Ct4 = reinterpret_cast<const float4*>(ws);
    float4* __restrict__ o4        = reinterpret_cast<float4*>(out);

    union { short8 s; unsigned u[4]; } zz;
    zz.u[0] = zz.u[1] = zz.u[2] = zz.u[3] = 0u;
    const short8 zero = zz.s;

    // ---- persistent fragments (loaded once; validated addressing) ----
    short8 B1_0, B1_1, B1_2, B1_3, B2_0, B2_1, B2_2, B2_3;   // A (GEMM1-T A-op)
    {
        float4 a0, a1;
        a0 = A4[lh*16 + 0*4 + hf*2]; a1 = A4[lh*16 + 0*4 + hf*2 + 1];
        B1_0 = pack8(a0, a1, false); B2_0 = (lg < 2) ? pack8(a0, a1, true) : zero;
        a0 = A4[lh*16 + 1*4 + hf*2]; a1 = A4[lh*16 + 1*4 + hf*2 + 1];
        B1_1 = pack8(a0, a1, false); B2_1 = (lg < 2) ? pack8(a0, a1, true) : zero;
        a0 = A4[lh*16 + 2*4 + hf*2]; a1 = A4[lh*16 + 2*4 + hf*2 + 1];
        B1_2 = pack8(a0, a1, false); B2_2 = (lg < 2) ? pack8(a0, a1, true) : zero;
        a0 = A4[lh*16 + 3*4 + hf*2]; a1 = A4[lh*16 + 3*4 + hf*2 + 1];
        B1_3 = pack8(a0, a1, false); B2_3 = (lg < 2) ? pack8(a0, a1, true) : zero;
    }
    short8 C1_0, C1_1, C1_2, C1_3, C2_0, C2_1, C2_2, C2_3;   // -C (GEMM2-T A-op)
    {
        float4 c0, c1;
        #define LOADC(n) \
            c0 = Ct4[((n)*16+lh)*4 + hf*2]; c1 = Ct4[((n)*16+lh)*4 + hf*2 + 1]; \
            c0.x=-c0.x; c0.y=-c0.y; c0.z=-c0.z; c0.w=-c0.w; \
            c1.x=-c1.x; c1.y=-c1.y; c1.z=-c1.z; c1.w=-c1.w; \
            C1_##n = pack8(c0, c1, false); \
            C2_##n = (lg < 2) ? pack8(c0, c1, true) : zero;
        LOADC(0) LOADC(1) LOADC(2) LOADC(3)
        #undef LOADC
    }

    size_t tile = (size_t)blockIdx.x * 4 + wv;   // 16-row tile index

    // ---- prologue: issue tile-0 loads (y 4x1KB + b 1x1KB) ----
    const float4* ysrc = y4 + tile * 256;
    float4 g0 = ysrc[l];
    float4 g1 = ysrc[64 + l];
    float4 g2 = ysrc[128 + l];
    float4 g3 = ysrc[192 + l];
    float4 gb = b4[tile * 64 + lh * 4 + lg];   // b[row lh][4lg..+3]

    #pragma unroll 1
    for (int s = 0; s < TPERW; ++s) {
        // ---- 1. commit y to LDS, XOR-swizzled (vmcnt wait lands here) ----
        yT[wv][0*4 + lg][lh ^ (0*4 + lg)] = g0;
        yT[wv][1*4 + lg][lh ^ (1*4 + lg)] = g1;
        yT[wv][2*4 + lg][lh ^ (2*4 + lg)] = g2;
        yT[wv][3*4 + lg][lh ^ (3*4 + lg)] = g3;
        const float4 bv = gb;

        // ---- 2. re-issue loads with tile s+1 (in flight during compute) ----
        if (s + 1 < TPERW) {
            const float4* yn = y4 + (tile + NWTOT) * 256;
            g0 = yn[l];
            g1 = yn[64 + l];
            g2 = yn[128 + l];
            g3 = yn[192 + l];
            gb = b4[(tile + NWTOT) * 64 + lh * 4 + lg];
        }

        // ---- 3. GEMM1-T: acc = A * Y^T; lane -> t[row lh][4lg+r] ----
        f32x4 acc = {0.f, 0.f, 0.f, 0.f};
        {
            short8 af;
            float4 f0, f1;
            f0 = yT[wv][lh][(0*4 + hf*2) ^ lh];
            f1 = yT[wv][lh][(0*4 + hf*2 + 1) ^ lh];
            af = pack8(f0, f1, lolane);
            acc = MF(B1_0, af, acc); acc = MF(B2_0, af, acc);
            f0 = yT[wv][lh][(1*4 + hf*2) ^ lh];
            f1 = yT[wv][lh][(1*4 + hf*2 + 1) ^ lh];
            af = pack8(f0, f1, lolane);
            acc = MF(B1_1, af, acc); acc = MF(B2_1, af, acc);
            f0 = yT[wv][lh][(2*4 + hf*2) ^ lh];
            f1 = yT[wv][lh][(2*4 + hf*2 + 1) ^ lh];
            af = pack8(f0, f1, lolane);
            acc = MF(B1_2, af, acc); acc = MF(B2_2, af, acc);
            f0 = yT[wv][lh][(3*4 + hf*2) ^ lh];
            f1 = yT[wv][lh][(3*4 + hf*2 + 1) ^ lh];
            af = pack8(f0, f1, lolane);
            acc = MF(B1_3, af, acc); acc = MF(B2_3, af, acc);
        }
        // t = T - b, in registers (lane holds row lh, cols 4lg..4lg+3)
        acc[0] -= bv.x; acc[1] -= bv.y; acc[2] -= bv.z; acc[3] -= bv.w;

        // ---- 4. t row-local bounce: 1 b128 write + 2 b128 reads ----
        tb[wv][lh][lg] = make_float4(acc[0], acc[1], acc[2], acc[3]);
        short8 TF;
        {
            const float4 t0 = tb[wv][lh][2*hf];
            const float4 t1 = tb[wv][lh][2*hf + 1];
            TF = pack8(t0, t1, lolane);
        }

        // ---- 5. GEMM2-T per strip n: X^T = Y^T - C^T T^T, in-place ----
        #define STRIP(n) { \
            const float4 sd = yT[wv][lh][((n)*4 + lg) ^ lh]; \
            f32x4 x = {sd.x, sd.y, sd.z, sd.w}; \
            x = MF(C1_##n, TF, x); x = MF(C2_##n, TF, x); \
            yT[wv][lh][((n)*4 + lg) ^ lh] = make_float4(x[0], x[1], x[2], x[3]); }
        STRIP(0) STRIP(1) STRIP(2) STRIP(3)
        #undef STRIP

        // ---- 6. staged stores: 4 x 1KB contiguous, NONTEMPORAL ----
        float4* odst = o4 + tile * 256;
        nt_store4(yT[wv][0*4 + lg][lh ^ (0*4 + lg)], &odst[l]);
        nt_store4(yT[wv][1*4 + lg][lh ^ (1*4 + lg)], &odst[64 + l]);
        nt_store4(yT[wv][2*4 + lg][lh ^ (2*4 + lg)], &odst[128 + l]);
        nt_store4(yT[wv][3*4 + lg][lh ^ (3*4 + lg)], &odst[192 + l]);

        tile += NWTOT;
    }
}

// ---------------------------------------------------------------------------
extern "C" void kernel_launch(void* const* d_in, const int* in_sizes, int n_in,
                              void* d_out, int out_size, void* d_ws, size_t ws_size,
                              hipStream_t stream) {
    const float* y = (const float*)d_in[0];   // (1048576, 64)
    const float* A = (const float*)d_in[1];   // (16, 64)
    const float* b = (const float*)d_in[2];   // (1048576, 16)
    float* out = (float*)d_out;               // (1048576, 64)
    float* ws  = (float*)d_ws;                // 1024 floats: Ct (64x16)

    precompute_kernel<<<1, 256, 0, stream>>>(A, ws);
    // 4096 blocks x 4 waves = 16384 waves, 4 tiles each, 16 rows/tile.
    apply_kernel<<<NBLK, 256, 0, stream>>>(y, b, A, ws, out);
}

// Round 21
// 139.333 us; speedup vs baseline: 2.4454x; 2.4454x over previous
//
#include <hip/hip_runtime.h>

#define BATCH   1048576
#define IN_DIM  64
#define OUT_DIM 16
#define NBLK    4096      // 4096 blocks x 4 waves = 16384 waves
#define NWTOT   16384
#define TPERW   4         // 65536 16-row tiles / 16384 waves

typedef __attribute__((ext_vector_type(8))) short short8;  // 8 bf16 = 4 VGPR
typedef __attribute__((ext_vector_type(4))) float f32x4;   // MFMA accumulator

// ---------------------------------------------------------------------------
// Kernel 1: Ct[k*16+i] = C[i][k] where C = (A A^T)^-1 A  (validated R1-R20).
// ---------------------------------------------------------------------------
__global__ __launch_bounds__(256) void precompute_kernel(
    const float* __restrict__ A, float* __restrict__ ws)
{
    __shared__ float sA[16][64];
    __shared__ float M[16][32];   // [S | I]
    __shared__ float fac[16];
    __shared__ int piv;

    const int tid = threadIdx.x;

    for (int i = tid; i < 1024; i += 256) sA[i >> 6][i & 63] = A[i];
    __syncthreads();

    {
        const int i = tid >> 4, j = tid & 15;
        float s = 0.f;
        #pragma unroll
        for (int k = 0; k < 64; ++k) s = fmaf(sA[i][k], sA[j][k], s);
        M[i][j] = s;
        M[i][16 + j] = (i == j) ? 1.f : 0.f;
    }
    __syncthreads();

    for (int p = 0; p < 16; ++p) {
        if (tid == 0) {
            int best = p;
            float bv = fabsf(M[p][p]);
            for (int r = p + 1; r < 16; ++r) {
                float v = fabsf(M[r][p]);
                if (v > bv) { bv = v; best = r; }
            }
            piv = best;
        }
        __syncthreads();
        if (tid < 32) {
            const int pr = piv;
            if (pr != p) { float t = M[p][tid]; M[p][tid] = M[pr][tid]; M[pr][tid] = t; }
        }
        __syncthreads();
        const float pv = M[p][p];
        __syncthreads();
        if (tid < 32) M[p][tid] *= (1.0f / pv);
        __syncthreads();
        if (tid < 16) fac[tid] = M[tid][p];
        __syncthreads();
        for (int e = tid; e < 512; e += 256) {
            const int r = e >> 5, c = e & 31;
            if (r != p) M[r][c] = fmaf(-fac[r], M[p][c], M[r][c]);
        }
        __syncthreads();
    }

    for (int e = tid; e < 1024; e += 256) {
        const int k = e >> 4, i = e & 15;
        float s = 0.f;
        #pragma unroll
        for (int j = 0; j < 16; ++j) s = fmaf(M[i][16 + j], sA[j][k], s);
        ws[e] = s;
    }
}

// ---------------------------------------------------------------------------
// bf16 truncation-split packing (validated R13-R18). hi*hi exact in f32 MFMA.
// ---------------------------------------------------------------------------
__device__ __forceinline__ unsigned pack2(float a, float b, bool lo) {
    unsigned ua = __float_as_uint(a), ub = __float_as_uint(b);
    if (lo) {
        ua = __float_as_uint(a - __uint_as_float(ua & 0xFFFF0000u));
        ub = __float_as_uint(b - __uint_as_float(ub & 0xFFFF0000u));
    }
    return (ua >> 16) | (ub & 0xFFFF0000u);
}
__device__ __forceinline__ short8 pack8(float4 p, float4 q, bool lo) {
    union { short8 s; unsigned u[4]; } r;
    r.u[0] = pack2(p.x, p.y, lo);
    r.u[1] = pack2(p.z, p.w, lo);
    r.u[2] = pack2(q.x, q.y, lo);
    r.u[3] = pack2(q.z, q.w, lo);
    return r.s;
}

#define MF(a, bb, cc) __builtin_amdgcn_mfma_f32_16x16x32_bf16((a), (bb), (cc), 0, 0, 0)

// ---------------------------------------------------------------------------
// Kernel 2: R18 base (validated 141.3 us) + DEPTH-2 staging prefetch.
// R20 calibration: effective BW = in-flight/latency; R14-R18 hold ~5KB/wave
// (1-deep) x ~13 waves = 65KB/CU -> measured 3.1 TB/s. Depth-2 doubles
// per-wave in-flight to ~10KB (two named sets g,h; refilled at commit with
// tile s+2), reaching the ~120KB/CU needed for ~6 TB/s even if occupancy
// drops to 12 waves/CU. launch_bounds(256,3) gives the allocator headroom
// for the +20 staging VGPRs (R20 lesson: forcing 8 waves/EU spills the
// resident fragments; this design's cap is 3-4 waves/SIMD).
// ---------------------------------------------------------------------------
__global__ __launch_bounds__(256, 3) void apply_kernel(
    const float* __restrict__ y, const float* __restrict__ b,
    const float* __restrict__ A, const float* __restrict__ ws,
    float* __restrict__ out)
{
    __shared__ float4 yT[4][16][17];   // y tile (row-major float4, pad 17)
    __shared__ float4 tb[4][16][5];    // t^T tile (row lh, 4 float4, pad 5)

    const int tid = threadIdx.x;
    const int wv = tid >> 6, l = tid & 63;
    const int lh = l & 15, lg = l >> 4;
    const int hf = lg & 1;
    const bool lolane = (lg >= 2);

    const float4* __restrict__ y4  = reinterpret_cast<const float4*>(y);
    const float4* __restrict__ b4  = reinterpret_cast<const float4*>(b);
    const float4* __restrict__ A4  = reinterpret_cast<const float4*>(A);
    const float4* __restrict__ Ct4 = reinterpret_cast<const float4*>(ws);
    float4* __restrict__ o4        = reinterpret_cast<float4*>(out);

    union { short8 s; unsigned u[4]; } zz;
    zz.u[0] = zz.u[1] = zz.u[2] = zz.u[3] = 0u;
    const short8 zero = zz.s;

    // ---- persistent fragments (loaded once; validated addressing) ----
    short8 B1_0, B1_1, B1_2, B1_3, B2_0, B2_1, B2_2, B2_3;   // A (GEMM1-T A-op)
    {
        float4 a0, a1;
        a0 = A4[lh*16 + 0*4 + hf*2]; a1 = A4[lh*16 + 0*4 + hf*2 + 1];
        B1_0 = pack8(a0, a1, false); B2_0 = (lg < 2) ? pack8(a0, a1, true) : zero;
        a0 = A4[lh*16 + 1*4 + hf*2]; a1 = A4[lh*16 + 1*4 + hf*2 + 1];
        B1_1 = pack8(a0, a1, false); B2_1 = (lg < 2) ? pack8(a0, a1, true) : zero;
        a0 = A4[lh*16 + 2*4 + hf*2]; a1 = A4[lh*16 + 2*4 + hf*2 + 1];
        B1_2 = pack8(a0, a1, false); B2_2 = (lg < 2) ? pack8(a0, a1, true) : zero;
        a0 = A4[lh*16 + 3*4 + hf*2]; a1 = A4[lh*16 + 3*4 + hf*2 + 1];
        B1_3 = pack8(a0, a1, false); B2_3 = (lg < 2) ? pack8(a0, a1, true) : zero;
    }
    short8 C1_0, C1_1, C1_2, C1_3, C2_0, C2_1, C2_2, C2_3;   // -C (GEMM2-T A-op)
    {
        float4 c0, c1;
        #define LOADC(n) \
            c0 = Ct4[((n)*16+lh)*4 + hf*2]; c1 = Ct4[((n)*16+lh)*4 + hf*2 + 1]; \
            c0.x=-c0.x; c0.y=-c0.y; c0.z=-c0.z; c0.w=-c0.w; \
            c1.x=-c1.x; c1.y=-c1.y; c1.z=-c1.z; c1.w=-c1.w; \
            C1_##n = pack8(c0, c1, false); \
            C2_##n = (lg < 2) ? pack8(c0, c1, true) : zero;
        LOADC(0) LOADC(1) LOADC(2) LOADC(3)
        #undef LOADC
    }

    size_t tile = (size_t)blockIdx.x * 4 + wv;   // 16-row tile index

    // ---- prologue: issue loads for tile (set g) and tile+NWTOT (set h) ----
    const float4* ys0 = y4 + tile * 256;
    float4 g0 = ys0[l];
    float4 g1 = ys0[64 + l];
    float4 g2 = ys0[128 + l];
    float4 g3 = ys0[192 + l];
    float4 gb = b4[tile * 64 + lh * 4 + lg];
    const float4* ys1 = y4 + (tile + NWTOT) * 256;
    float4 h0 = ys1[l];
    float4 h1 = ys1[64 + l];
    float4 h2 = ys1[128 + l];
    float4 h3 = ys1[192 + l];
    float4 hb = b4[(tile + NWTOT) * 64 + lh * 4 + lg];

    // Tile body: commit SET to LDS, optionally refill SET from tile+2*NWTOT,
    // compute (R18-identical), staged stores, advance tile.
    #define TILE_BODY(S0, S1, S2, S3, SB, REFILL) {                           \
        yT[wv][0*4 + lg][lh] = S0;                                            \
        yT[wv][1*4 + lg][lh] = S1;                                            \
        yT[wv][2*4 + lg][lh] = S2;                                            \
        yT[wv][3*4 + lg][lh] = S3;                                            \
        const float4 bv = SB;                                                 \
        if (REFILL) {                                                         \
            const float4* yn = y4 + (tile + 2 * NWTOT) * 256;                 \
            S0 = yn[l];                                                       \
            S1 = yn[64 + l];                                                  \
            S2 = yn[128 + l];                                                 \
            S3 = yn[192 + l];                                                 \
            SB = b4[(tile + 2 * NWTOT) * 64 + lh * 4 + lg];                   \
        }                                                                     \
        f32x4 acc = {0.f, 0.f, 0.f, 0.f};                                     \
        {                                                                     \
            short8 af;                                                        \
            float4 f0, f1;                                                    \
            f0 = yT[wv][lh][0*4 + hf*2]; f1 = yT[wv][lh][0*4 + hf*2 + 1];     \
            af = pack8(f0, f1, lolane);                                       \
            acc = MF(B1_0, af, acc); acc = MF(B2_0, af, acc);                 \
            f0 = yT[wv][lh][1*4 + hf*2]; f1 = yT[wv][lh][1*4 + hf*2 + 1];     \
            af = pack8(f0, f1, lolane);                                       \
            acc = MF(B1_1, af, acc); acc = MF(B2_1, af, acc);                 \
            f0 = yT[wv][lh][2*4 + hf*2]; f1 = yT[wv][lh][2*4 + hf*2 + 1];     \
            af = pack8(f0, f1, lolane);                                       \
            acc = MF(B1_2, af, acc); acc = MF(B2_2, af, acc);                 \
            f0 = yT[wv][lh][3*4 + hf*2]; f1 = yT[wv][lh][3*4 + hf*2 + 1];     \
            af = pack8(f0, f1, lolane);                                       \
            acc = MF(B1_3, af, acc); acc = MF(B2_3, af, acc);                 \
        }                                                                     \
        acc[0] -= bv.x; acc[1] -= bv.y; acc[2] -= bv.z; acc[3] -= bv.w;       \
        tb[wv][lh][lg] = make_float4(acc[0], acc[1], acc[2], acc[3]);         \
        short8 TF;                                                            \
        {                                                                     \
            const float4 t0 = tb[wv][lh][2*hf];                               \
            const float4 t1 = tb[wv][lh][2*hf + 1];                           \
            TF = pack8(t0, t1, lolane);                                       \
        }                                                                     \
        {                                                                     \
            const float4 sd0 = yT[wv][lh][0*4 + lg];                          \
            f32x4 x0 = {sd0.x, sd0.y, sd0.z, sd0.w};                          \
            x0 = MF(C1_0, TF, x0); x0 = MF(C2_0, TF, x0);                     \
            yT[wv][lh][0*4 + lg] = make_float4(x0[0], x0[1], x0[2], x0[3]);   \
            const float4 sd1 = yT[wv][lh][1*4 + lg];                          \
            f32x4 x1 = {sd1.x, sd1.y, sd1.z, sd1.w};                          \
            x1 = MF(C1_1, TF, x1); x1 = MF(C2_1, TF, x1);                     \
            yT[wv][lh][1*4 + lg] = make_float4(x1[0], x1[1], x1[2], x1[3]);   \
            const float4 sd2 = yT[wv][lh][2*4 + lg];                          \
            f32x4 x2 = {sd2.x, sd2.y, sd2.z, sd2.w};                          \
            x2 = MF(C1_2, TF, x2); x2 = MF(C2_2, TF, x2);                     \
            yT[wv][lh][2*4 + lg] = make_float4(x2[0], x2[1], x2[2], x2[3]);   \
            const float4 sd3 = yT[wv][lh][3*4 + lg];                          \
            f32x4 x3 = {sd3.x, sd3.y, sd3.z, sd3.w};                          \
            x3 = MF(C1_3, TF, x3); x3 = MF(C2_3, TF, x3);                     \
            yT[wv][lh][3*4 + lg] = make_float4(x3[0], x3[1], x3[2], x3[3]);   \
        }                                                                     \
        float4* odst = o4 + tile * 256;                                       \
        odst[l]       = yT[wv][0*4 + lg][lh];                                 \
        odst[64 + l]  = yT[wv][1*4 + lg][lh];                                 \
        odst[128 + l] = yT[wv][2*4 + lg][lh];                                 \
        odst[192 + l] = yT[wv][3*4 + lg][lh];                                 \
        tile += NWTOT;                                                        \
    }

    // TPERW = 4, unrolled as 2 x (g-body, h-body); refills only on pass 0.
    #pragma unroll 1
    for (int s = 0; s < 2; ++s) {
        const bool refill = (s == 0);
        TILE_BODY(g0, g1, g2, g3, gb, refill)   // tiles base+0, base+2
        TILE_BODY(h0, h1, h2, h3, hb, refill)   // tiles base+1, base+3
    }
    #undef TILE_BODY
}

// ---------------------------------------------------------------------------
extern "C" void kernel_launch(void* const* d_in, const int* in_sizes, int n_in,
                              void* d_out, int out_size, void* d_ws, size_t ws_size,
                              hipStream_t stream) {
    const float* y = (const float*)d_in[0];   // (1048576, 64)
    const float* A = (const float*)d_in[1];   // (16, 64)
    const float* b = (const float*)d_in[2];   // (1048576, 16)
    float* out = (float*)d_out;               // (1048576, 64)
    float* ws  = (float*)d_ws;                // 1024 floats: Ct (64x16)

    precompute_kernel<<<1, 256, 0, stream>>>(A, ws);
    // 4096 blocks x 4 waves = 16384 waves, 4 tiles each, 16 rows/tile.
    apply_kernel<<<NBLK, 256, 0, stream>>>(y, b, A, ws, out);
}